// Round 4
// baseline (817.985 us; speedup 1.0000x reference)
//
#include <hip/hip_runtime.h>

typedef unsigned int uint32;
typedef __attribute__((ext_vector_type(8))) short bf16x8;
typedef __attribute__((ext_vector_type(4))) float f32x4;

// ---------------------------------------------------------------------------
// Sizes: B=2, L=256, E=512, H=8, D=64.  SCALE = 0.125
// ---------------------------------------------------------------------------

// ===========================================================================
// Wr f32 -> bf16 (RNE). 1024x512 = 524288 elems, 4 per thread.
// ===========================================================================
__device__ __forceinline__ uint32 bf_rne(uint32 u) {
  return (u + 0x7fffu + ((u >> 16) & 1u)) >> 16;
}

__global__ void cvt_wr_kernel(const float* __restrict__ Wr, unsigned short* __restrict__ WrBf) {
  int idx = blockIdx.x * 256 + threadIdx.x;   // [0, 131072)
  const uint4* src = (const uint4*)Wr;
  uint4 x = src[idx];
  uint2 o;
  o.x = bf_rne(x.x) | (bf_rne(x.y) << 16);
  o.y = bf_rne(x.z) | (bf_rne(x.w) << 16);
  ((uint2*)WrBf)[idx] = o;
}

// ===========================================================================
// Projection GEMM: Y[m,n] = (sum_k X[m,k] * W[n,k] + bias[n]) * scale
// M=N=K=512.  BM=BN=64, BK=16, 256 threads, 4x4 per thread.
// grid.z selects (X,W,bias,Y) triple (q/k/v); also reused for Wo.
// ===========================================================================
__global__ __launch_bounds__(256) void proj_kernel(
    const float* __restrict__ X0, const float* __restrict__ W0, const float* __restrict__ b0, float* __restrict__ Y0,
    const float* __restrict__ X1, const float* __restrict__ W1, const float* __restrict__ b1, float* __restrict__ Y1,
    const float* __restrict__ X2, const float* __restrict__ W2, const float* __restrict__ b2, float* __restrict__ Y2,
    float scale0) {
  int z = blockIdx.z;
  const float* X = (z == 0) ? X0 : (z == 1) ? X1 : X2;
  const float* W = (z == 0) ? W0 : (z == 1) ? W1 : W2;
  const float* bias = (z == 0) ? b0 : (z == 1) ? b1 : b2;
  float* Y = (z == 0) ? Y0 : (z == 1) ? Y1 : Y2;
  float scale = (z == 0) ? scale0 : 1.0f;

  __shared__ float Xs[16][68];
  __shared__ float Ws[16][68];

  int tid = threadIdx.x;
  int tx = tid & 15, ty = tid >> 4;
  int m0 = blockIdx.x * 64, n0 = blockIdx.y * 64;

  float acc[4][4] = {};

  for (int k0 = 0; k0 < 512; k0 += 16) {
#pragma unroll
    for (int u = 0; u < 4; ++u) {
      int idx = tid + u * 256;           // [0,1024)
      int ml = idx >> 4, kl = idx & 15;
      Xs[kl][ml] = X[(size_t)(m0 + ml) * 512 + k0 + kl];
      Ws[kl][ml] = W[(size_t)(n0 + ml) * 512 + k0 + kl];
    }
    __syncthreads();
#pragma unroll
    for (int kk = 0; kk < 16; ++kk) {
      float4 a = *(const float4*)&Xs[kk][ty * 4];
      float4 w = *(const float4*)&Ws[kk][tx * 4];
      float av[4] = {a.x, a.y, a.z, a.w};
      float wv[4] = {w.x, w.y, w.z, w.w};
#pragma unroll
      for (int i = 0; i < 4; ++i)
#pragma unroll
        for (int jj = 0; jj < 4; ++jj)
          acc[i][jj] += av[i] * wv[jj];
    }
    __syncthreads();
  }
#pragma unroll
  for (int i = 0; i < 4; ++i) {
    int m = m0 + ty * 4 + i;
#pragma unroll
    for (int jj = 0; jj < 4; ++jj) {
      int n = n0 + tx * 4 + jj;
      Y[(size_t)m * 512 + n] = (acc[i][jj] + bias[n]) * scale;
    }
  }
}

// ===========================================================================
// Fused relation-GEMM + score kernel, v5: 8 waves, 2 passes, XOR-swizzled LDS.
//  - 2048 blocks of 512 threads; block = (b, j, i-block-of-64).
//  - A-tile (64x512 f32) converted to bf16, staged into LDS ONCE (stride 512,
//    XOR swizzle idx ^ ((row&7)<<3): ds_write_b128 and ds_read_b128 both
//    bank-conflict-free; v4's stride-520 had 8.39M conflict cycles).
//  - 8 waves cover 512 of the 1024 N-cols per pass; 2 passes (head-pairs
//    {0,1} then {2,3}).  Per wave: 64M x 64N, acc 64 f32.  Same LDS bytes as
//    v4 amortized over 2x waves -> 4 waves/SIMD (was 2): latency hiding.
//  - Pass 0 pipelined: depth-2 register prefetch of the A f32 stream, one
//    __syncthreads per 64-col chunk (chunks have disjoint LDS; no WAR).
//  - Pass 1 barrier-free; B fragments (Wr bf16, L2-hot) reg-prefetched.
// Epilogue per pass: score = sum_d (q+Prq)(k+Prk), 16-lane shuffle reduce,
// cross-wave (d-half) combine through LDS scores[pass][...], scatter to
// attn[b][i][j][h] raw scores.  4 heads' epilogues run concurrently.
// ===========================================================================
__global__ __launch_bounds__(512, 4) void rel_score_kernel(
    const float* __restrict__ rel,            // [B][j:256][i:256][512]
    const unsigned short* __restrict__ wrbf,  // [1024][512] bf16
    const float* __restrict__ qws,            // [B*256][512] (pre-scaled)
    const float* __restrict__ kws,            // [B*256][512]
    float* __restrict__ attn)                 // [B][i][j][H] raw scores
{
  __shared__ unsigned short As[64 * 512];     // 64 KB, XOR-swizzled
  __shared__ float scores[2][8][64];          // [pass][wave][m], 4 KB

  const int tid = threadIdx.x;                // 0..511
  const int lane = tid & 63;
  const int w = tid >> 6;                     // wave 0..7
  const int wvl = w & 3;
  const int mt = blockIdx.x;                  // [0, 2048)
  const int b = mt >> 10;
  const int j = (mt >> 2) & 255;
  const int i0 = (mt & 3) << 6;

  const float* Abase = rel + (size_t)mt * (64 * 512);

  const int t15 = lane & 15;
  const int kq = (lane >> 4) * 8;
  const int rswz = (t15 & 7) << 3;            // read-side XOR (short-index bits 3-5)

  // Per-fc global B row pointers for pass 0 (hp = w>>2); pass 1 adds 131072.
  const unsigned short* bptr[4];
#pragma unroll
  for (int fc = 0; fc < 4; ++fc) {
    int g = (wvl & 1) * 4 + fc;
    int head0 = (w >> 2) * 2 + (wvl >> 1);    // head for pass 0
    int wr_row = (g & 1) * 512 + head0 * 64 + (g >> 1) * 16 + t15;
    bptr[fc] = wrbf + (size_t)wr_row * 512 + kq;
  }

  // A staging: thread -> (row, 8-f32 col group)
  const int arow = tid >> 3;                  // 0..63
  const int ak8 = (tid & 7) * 8;              // 0..56
  const uint4* aq = (const uint4*)(Abase + (size_t)arow * 512 + ak8);
  const int wbase = arow * 512 + ak8;         // LDS short-index base
  const int wswz = (arow & 7) << 3;           // write-side XOR

  f32x4 acc[4][4];

  // ---- epilogue: score = sum_d (q + Prq)(k + Prk); pass p covers heads 4p.. ----
  auto epilogue = [&](int p) {
    const int head = (2 * p + (w >> 2)) * 2 + (wvl >> 1);
    const int dbase = (wvl & 1) * 32;
    const float* qbase = qws + ((size_t)(b * 256 + i0)) * 512 + head * 64;
    const float* krow = kws + ((size_t)(b * 256 + j)) * 512 + head * 64;
    const int rgrp = lane >> 4;
#pragma unroll
    for (int fr = 0; fr < 4; ++fr) {
#pragma unroll
      for (int r = 0; r < 4; ++r) {
        int m = fr * 16 + rgrp * 4 + r;
        float s = 0.f;
#pragma unroll
        for (int p2 = 0; p2 < 2; ++p2) {
          int d = dbase + p2 * 16 + t15;
          float qv = qbase[(size_t)m * 512 + d];
          float kv = krow[d];
          s += (qv + acc[fr][p2 * 2][r]) * (kv + acc[fr][p2 * 2 + 1][r]);
        }
        s += __shfl_xor(s, 1);
        s += __shfl_xor(s, 2);
        s += __shfl_xor(s, 4);
        s += __shfl_xor(s, 8);
        if (t15 == 0) scores[p][w][m] = s;
      }
    }
    __syncthreads();
    if (tid < 256) {
      int hl = tid >> 6, m = tid & 63;       // hl = head offset within pass
      float sc = scores[p][hl * 2][m] + scores[p][hl * 2 + 1][m];
      attn[(((size_t)(b * 256 + i0 + m)) * 256 + j) * 8 + 4 * p + hl] = sc;
    }
  };

  // ======================= pass 0: stage + compute ==========================
#pragma unroll
  for (int a = 0; a < 4; ++a)
#pragma unroll
    for (int c = 0; c < 4; ++c)
      acc[a][c] = (f32x4){0.f, 0.f, 0.f, 0.f};

  // depth-2 A prefetch (chunk = 64 f32 cols = 16 uint4 stride per row-chunk)
  uint4 c0a = aq[0], c0b = aq[1];             // chunk 0
  uint4 c1a = aq[16], c1b = aq[17];           // chunk 1

#pragma unroll
  for (int k = 0; k < 8; ++k) {
    const int k0 = k * 64;
    // B fragments for this iter (L2-hot)
    bf16x8 bfr[2][4];
#pragma unroll
    for (int kh = 0; kh < 2; ++kh)
#pragma unroll
      for (int fc = 0; fc < 4; ++fc)
        bfr[kh][fc] = *(const bf16x8*)(bptr[fc] + k0 + kh * 32);
    // convert chunk-k registers -> bf16, store 16B to swizzled LDS
    {
      uint4 o;
      o.x = (c0a.y & 0xffff0000u) | (c0a.x >> 16);
      o.y = (c0a.w & 0xffff0000u) | (c0a.z >> 16);
      o.z = (c0b.y & 0xffff0000u) | (c0b.x >> 16);
      o.w = (c0b.w & 0xffff0000u) | (c0b.z >> 16);
      *(uint4*)&As[(wbase + k0) ^ wswz] = o;
    }
    // rotate prefetch: chunk k+1 -> current, issue chunk k+2
    c0a = c1a;
    c0b = c1b;
    if (k < 6) {
      c1a = aq[(k + 2) * 16];
      c1b = aq[(k + 2) * 16 + 1];
    }
    __syncthreads();
    // MFMA on chunk k
#pragma unroll
    for (int kh = 0; kh < 2; ++kh) {
      int kk = k0 + kh * 32 + kq;
      bf16x8 af[4];
#pragma unroll
      for (int fr = 0; fr < 4; ++fr)
        af[fr] = *(const bf16x8*)&As[((fr * 16 + t15) * 512 + kk) ^ rswz];
#pragma unroll
      for (int fr = 0; fr < 4; ++fr)
#pragma unroll
        for (int fc = 0; fc < 4; ++fc)
          acc[fr][fc] = __builtin_amdgcn_mfma_f32_16x16x32_bf16(
              af[fr], bfr[kh][fc], acc[fr][fc], 0, 0, 0);
    }
  }
  epilogue(0);

  // ================= pass 1: barrier-free, A resident in LDS ================
#pragma unroll
  for (int a = 0; a < 4; ++a)
#pragma unroll
    for (int c = 0; c < 4; ++c)
      acc[a][c] = (f32x4){0.f, 0.f, 0.f, 0.f};

  {
    const int hofs = 131072;  // +2 head-pairs * 128 rows * 512

    bf16x8 bfr[2][4];
#pragma unroll
    for (int kh = 0; kh < 2; ++kh)
#pragma unroll
      for (int fc = 0; fc < 4; ++fc)
        bfr[kh][fc] = *(const bf16x8*)(bptr[fc] + hofs + kh * 32);

#pragma unroll
    for (int k = 0; k < 8; ++k) {
      const int k0 = k * 64;
      bf16x8 bnx[2][4];
      if (k < 7) {
#pragma unroll
        for (int kh = 0; kh < 2; ++kh)
#pragma unroll
          for (int fc = 0; fc < 4; ++fc)
            bnx[kh][fc] = *(const bf16x8*)(bptr[fc] + hofs + k0 + 64 + kh * 32);
      }
#pragma unroll
      for (int kh = 0; kh < 2; ++kh) {
        int kk = k0 + kh * 32 + kq;
        bf16x8 af[4];
#pragma unroll
        for (int fr = 0; fr < 4; ++fr)
          af[fr] = *(const bf16x8*)&As[((fr * 16 + t15) * 512 + kk) ^ rswz];
#pragma unroll
        for (int fr = 0; fr < 4; ++fr)
#pragma unroll
          for (int fc = 0; fc < 4; ++fc)
            acc[fr][fc] = __builtin_amdgcn_mfma_f32_16x16x32_bf16(
                af[fr], bfr[kh][fc], acc[fr][fc], 0, 0, 0);
      }
      if (k < 7) {
#pragma unroll
        for (int kh = 0; kh < 2; ++kh)
#pragma unroll
          for (int fc = 0; fc < 4; ++fc)
            bfr[kh][fc] = bnx[kh][fc];
      }
    }
  }
  epilogue(1);
}

// ===========================================================================
// Fused masked softmax (over j) + AV contraction.  Block = (b,i).
// Writes normalized weights to attn (output #2) and o1[b,i,:].
// ===========================================================================
__global__ __launch_bounds__(256) void softmax_av_kernel(
    float* __restrict__ attn, const int* __restrict__ adj,
    const float* __restrict__ vws, float* __restrict__ o1) {
  __shared__ float sl[2048];
  __shared__ int msk[256];
  int bi = blockIdx.x;                         // b*256 + i
  int b = bi >> 8;
  float* base = attn + (size_t)bi * 2048;
  const int* abase = adj + (size_t)bi * 256;
  int tid = threadIdx.x;
#pragma unroll
  for (int u = 0; u < 8; ++u) sl[tid + u * 256] = base[tid + u * 256];
  msk[tid] = abase[tid];
  __syncthreads();
  int h = tid >> 5, l5 = tid & 31;
  float mx = -INFINITY;
#pragma unroll
  for (int u = 0; u < 8; ++u) {
    int jj = l5 + u * 32;
    if (msk[jj] != 1) mx = fmaxf(mx, sl[jj * 8 + h]);
  }
#pragma unroll
  for (int off = 16; off >= 1; off >>= 1) mx = fmaxf(mx, __shfl_xor(mx, off));
  float ev[8];
  float sum = 0.f;
#pragma unroll
  for (int u = 0; u < 8; ++u) {
    int jj = l5 + u * 32;
    float e = (msk[jj] != 1) ? __expf(sl[jj * 8 + h] - mx) : 0.f;
    ev[u] = e;
    sum += e;
  }
#pragma unroll
  for (int off = 16; off >= 1; off >>= 1) sum += __shfl_xor(sum, off);
  float inv = (sum > 0.f) ? (1.f / sum) : 0.f;
#pragma unroll
  for (int u = 0; u < 8; ++u) {
    int jj = l5 + u * 32;
    sl[jj * 8 + h] = ev[u] * inv;
  }
  __syncthreads();
  // write normalized weights (output #2)
#pragma unroll
  for (int u = 0; u < 8; ++u) base[tid + u * 256] = sl[tid + u * 256];
  // AV from LDS weights
  const float* vbase = vws + (size_t)b * (256 * 512);
  int e0 = tid, e1 = tid + 256;
  int h0 = e0 >> 6, h1 = e1 >> 6;
  float a0 = 0.f, a1 = 0.f;
  for (int jj = 0; jj < 256; ++jj) {
    float w0 = sl[jj * 8 + h0];
    float w1 = sl[jj * 8 + h1];
    const float* vr = vbase + (size_t)jj * 512;
    a0 += w0 * vr[e0];
    a1 += w1 * vr[e1];
  }
  float* orow = o1 + (size_t)bi * 512;
  orow[e0] = a0;
  orow[e1] = a1;
}

// ===========================================================================
// Launch
// ===========================================================================
extern "C" void kernel_launch(void* const* d_in, const int* in_sizes, int n_in,
                              void* d_out, int out_size, void* d_ws, size_t ws_size,
                              hipStream_t stream) {
  const float* queries = (const float*)d_in[0];
  const float* keys    = (const float*)d_in[1];
  const float* values  = (const float*)d_in[2];
  const float* relation = (const float*)d_in[3];
  const int*   adj     = (const int*)d_in[4];
  const float* Wq = (const float*)d_in[5];
  const float* bq = (const float*)d_in[6];
  const float* Wk = (const float*)d_in[7];
  const float* bk = (const float*)d_in[8];
  const float* Wv = (const float*)d_in[9];
  const float* bv = (const float*)d_in[10];
  const float* Wr = (const float*)d_in[11];
  const float* Wo = (const float*)d_in[12];
  const float* bo = (const float*)d_in[13];

  float* out  = (float*)d_out;            // [2*256][512]
  float* attn = out + 262144;             // [2][256][256][8]

  float* ws  = (float*)d_ws;
  float* qws = ws;                        // 262144
  float* kws = ws + 262144;
  float* vws = ws + 524288;
  float* o1  = ws + 786432;
  unsigned short* wrbf = (unsigned short*)(ws + 1048576);  // 524288 bf16

  cvt_wr_kernel<<<dim3(512), dim3(256), 0, stream>>>(Wr, wrbf);

  proj_kernel<<<dim3(8, 8, 3), dim3(256), 0, stream>>>(
      queries, Wq, bq, qws,
      keys,    Wk, bk, kws,
      values,  Wv, bv, vws,
      0.125f);

  rel_score_kernel<<<dim3(2048), dim3(512), 0, stream>>>(relation, wrbf, qws, kws, attn);

  softmax_av_kernel<<<dim3(512), dim3(256), 0, stream>>>(attn, adj, vws, o1);

  proj_kernel<<<dim3(8, 8, 1), dim3(256), 0, stream>>>(
      o1, Wo, bo, out,
      nullptr, nullptr, nullptr, nullptr,
      nullptr, nullptr, nullptr, nullptr,
      1.0f);
}